// Round 15
// baseline (24.427 us; speedup 1.0000x reference)
//
#include <hip/hip_runtime.h>

typedef _Float16 f16;
typedef f16 f16x8 __attribute__((ext_vector_type(8)));
typedef float f32x4 __attribute__((ext_vector_type(4)));

constexpr int Bc = 32, Nc = 1024, Dc = 64, Hc = 4, Ec = 16;
constexpr int HPL = 1032;  // attn LDS hv pitch (f16) = 129 float4 rows

// ---------------------------------------------------------------------------
// Kernel 1: round-13 proj2 with XCD-aligned block decode.
// NEW: bh = blk & 127, chunk = blk >> 7  ->  all 8 blocks of a bh sit at
// linear ids == bh (mod 8) -> same XCD as the attn block for bh (id bh+128*y).
// h16t[bh] + s vectors therefore stay in the LOCAL XCD L2 for the consumer.
// ---------------------------------------------------------------------------
__global__ __launch_bounds__(256) void gat_proj2(const float* __restrict__ input,
                                                 const float* __restrict__ W,
                                                 const float* __restrict__ a,
                                                 f16* __restrict__ h16t,
                                                 float* __restrict__ s_src,
                                                 float* __restrict__ s_dst) {
    __shared__ float W_lds[Dc * Ec];          // 4 KB
    __shared__ float a_lds[2 * Ec];
    __shared__ alignas(16) f16 T[Ec][136];    // 128 + 8 pad

    const int tid  = threadIdx.x;
    const int blk  = blockIdx.x;           // 0..1023
    const int bh   = blk & 127;            // XCD-aligned decode (see header)
    const int hh   = bh & (Hc - 1);
    const int b    = bh >> 2;
    const int n0   = (blk >> 7) * 128;
    const int half = tid & 1;
    const int nl   = tid >> 1;
    const int n    = n0 + nl;

    ((float4*)W_lds)[tid] = ((const float4*)(W + hh * Dc * Ec))[tid];
    if (tid < 2 * Ec) a_lds[tid] = a[tid];
    __syncthreads();

    const float4* in_row = (const float4*)(input + ((size_t)b * Nc + n) * Dc);

    float acc[8];
#pragma unroll
    for (int e = 0; e < 8; ++e) acc[e] = 0.f;

#pragma unroll
    for (int d4 = 0; d4 < Dc / 4; ++d4) {
        float4 x = in_row[d4];
        float xs[4] = {x.x, x.y, x.z, x.w};
#pragma unroll
        for (int k = 0; k < 4; ++k) {
            const float xv = xs[k];
            const float* wrow = &W_lds[(d4 * 4 + k) * Ec + half * 8];
#pragma unroll
            for (int e = 0; e < 8; ++e) acc[e] = fmaf(xv, wrow[e], acc[e]);
        }
    }

    {
        float sd = 0.f, ss = 0.f;
#pragma unroll
        for (int e = 0; e < 8; ++e) {
            sd = fmaf(acc[e], a_lds[half * 8 + e],      sd);
            ss = fmaf(acc[e], a_lds[16 + half * 8 + e], ss);
        }
        sd += __shfl_xor(sd, 1, 64);
        ss += __shfl_xor(ss, 1, 64);
        if (half == 0) {
            s_dst[bh * Nc + n] = sd;
            s_src[bh * Nc + n] = ss;
        }
    }

#pragma unroll
    for (int e = 0; e < 8; ++e) T[half * 8 + e][nl] = (f16)acc[e];
    __syncthreads();

    {
        const int e2 = tid >> 4;
        const int ch = tid & 15;
        *(float4*)(h16t + (size_t)bh * Ec * Nc + (size_t)e2 * Nc + n0 + ch * 8) =
            *(const float4*)(&T[e2][ch * 8]);
    }
}

// ---------------------------------------------------------------------------
// Kernel 2: UNCHANGED round-14 attn10.  P_ij = v_j * max(w_j, C_i) exact;
// B-operands carry v (hv = v*h, den-B = v8); inner loop = 4 pk_max + 2 MFMA.
// ---------------------------------------------------------------------------
__global__ __launch_bounds__(512) void gat_attn10(const f16* __restrict__ h16t,
                                                  const float* __restrict__ s_src,
                                                  const float* __restrict__ s_dst,
                                                  float* __restrict__ out) {
    __shared__ alignas(16) f16 hv_t[Ec * HPL];   // 33 KB (v-scaled h)
    __shared__ alignas(16) f16 w_lds[Nc];        // 2 KB
    __shared__ alignas(16) f16 v_lds[Nc];        // 2 KB
    __shared__ float red[8];

    const int bh    = blockIdx.x;      // 0..127
    const int ihalf = blockIdx.y;      // 0..1
    const int tid   = threadIdx.x;
    const int lane  = tid & 63;
    const int wave  = tid >> 6;        // 0..7
    const int row   = lane & 15;
    const int quad  = lane >> 4;

    // ---- issue h chunk loads early (latency hides under reduce/exp) ----
    f16x8 h8[4];
    {
        const float4* src = (const float4*)(h16t + (size_t)bh * Ec * Nc);
#pragma unroll
        for (int cc = 0; cc < 4; ++cc) {
            float4 t = src[cc * 512 + tid];
            h8[cc] = *(f16x8*)&t;
        }
    }

    // ---- block max of s_dst ----
    const float sd0 = s_dst[bh * Nc + tid];
    const float sd1 = s_dst[bh * Nc + 512 + tid];
    {
        float m = fmaxf(sd0, sd1);
#pragma unroll
        for (int off = 1; off < 64; off <<= 1) m = fmaxf(m, __shfl_xor(m, off, 64));
        if (lane == 0) red[wave] = m;
    }
    __syncthreads();
    float maxd = red[0];
#pragma unroll
    for (int w = 1; w < 8; ++w) maxd = fmaxf(maxd, red[w]);

    // ---- w, v into LDS ----
    w_lds[tid]       = (f16)__expf(0.8f * (sd0 - maxd));
    w_lds[512 + tid] = (f16)__expf(0.8f * (sd1 - maxd));
    v_lds[tid]       = (f16)__expf(0.2f * (sd0 - maxd));
    v_lds[512 + tid] = (f16)__expf(0.2f * (sd1 - maxd));

    // ---- per-row C_i ----
    const int ibase = ihalf * 512 + wave * 64;
    f16x8 C8[4];
#pragma unroll
    for (int it = 0; it < 4; ++it) {
        const float si = s_src[bh * Nc + ibase + it * 16 + row];
        const float c1 = si + maxd;
        const float Cf = (c1 >= 0.f) ? __expf(-0.8f * c1) : 1.0f;
        const f16 ch = (f16)Cf;
        C8[it] = (f16x8){ch, ch, ch, ch, ch, ch, ch, ch};
    }
    __syncthreads();   // v_lds ready for hv build

    // ---- build hv = v * h into LDS ----
    {
        float4* dst = (float4*)hv_t;
#pragma unroll
        for (int cc = 0; cc < 4; ++cc) {
            const int c  = cc * 512 + tid;     // 0..2047
            const int e  = c >> 7;
            const int jc = c & 127;
            const f16x8 v8 = *(const f16x8*)(&v_lds[jc * 8]);
            f16x8 hv = h8[cc] * v8;            // 4 pk muls
            dst[e * 129 + jc] = *(float4*)&hv;
        }
    }
    __syncthreads();

    f32x4 accN[4] = {};
    f32x4 accD[4] = {};

    const f16* wp = w_lds + quad * 8;
    const f16* vp = v_lds + quad * 8;
    const f16* bp = hv_t + row * HPL + quad * 8;

#pragma unroll 4
    for (int kt = 0; kt < 32; ++kt) {
        const f16x8 w8  = *(const f16x8*)(wp + kt * 32);
        const f16x8 v8  = *(const f16x8*)(vp + kt * 32);
        const f16x8 hv8 = *(const f16x8*)(bp + kt * 32);
#pragma unroll
        for (int it = 0; it < 4; ++it) {
            const f16x8 pm = __builtin_elementwise_max(w8, C8[it]);   // 4 pk instrs
            accN[it] = __builtin_amdgcn_mfma_f32_16x16x32_f16(pm, hv8, accN[it], 0, 0, 0);
            accD[it] = __builtin_amdgcn_mfma_f32_16x16x32_f16(pm, v8,  accD[it], 0, 0, 0);
        }
    }

    // ---- epilogue: D row = quad*4 + r, col = row ----
#pragma unroll
    for (int it = 0; it < 4; ++it) {
#pragma unroll
        for (int r = 0; r < 4; ++r) {
            const float inv = __builtin_amdgcn_rcpf(accD[it][r]);
            const int i = ibase + it * 16 + quad * 4 + r;
            out[((size_t)(bh * Nc + i)) * Ec + row] = accN[it][r] * inv;
        }
    }
}

extern "C" void kernel_launch(void* const* d_in, const int* in_sizes, int n_in,
                              void* d_out, int out_size, void* d_ws, size_t ws_size,
                              hipStream_t stream) {
    const float* input = (const float*)d_in[0];
    // d_in[1] = adj : UNUSED by the reference
    const float* W = (const float*)d_in[2];
    const float* a = (const float*)d_in[3];
    float* out = (float*)d_out;

    char* ws = (char*)d_ws;
    f16*   h16t  = (f16*)(ws);                       // 4,194,304 B
    float* s_src = (float*)(ws + 4194304);           // 524,288 B
    float* s_dst = (float*)(ws + 4194304 + 524288);  // 524,288 B

    gat_proj2<<<dim3(1024), dim3(256), 0, stream>>>(input, W, a, h16t, s_src, s_dst);
    gat_attn10<<<dim3(Bc * Hc, 2), dim3(512), 0, stream>>>(h16t, s_src, s_dst, out);
}